// Round 26
// baseline (417.694 us; speedup 1.0000x reference)
//
#include <hip/hip_runtime.h>
#include <hip/hip_bf16.h>
#include <cstddef>
#include <cstdint>

#define BS_     32
#define NUM_R_  10
#define NUM_P_  36
#define SL_Q_   20
#define IMG_F_  2048
#define TDIM_   600
#define TDIMP_  640     // 600 padded to %64==0
#define LSTM_   512
#define CAT_    2648
#define CATP_K  2688    // 2648 padded to %64==0 (42 x 64)
#define CATP_R  2688    // B-row pad for 128-tiles (himg)
#define CATP_R8 2816    // B-row pad (mode-1 B rows; 21x128=2688 <= 2816)

typedef unsigned short ushort_t;
typedef __attribute__((ext_vector_type(8))) short short8;
typedef __attribute__((ext_vector_type(4))) float f32x4;

__device__ __forceinline__ ushort_t f2bf(float f) {
  union { float f; unsigned int u; } v; v.f = f;
  unsigned int r = v.u + 0x7fff + ((v.u >> 16) & 1);
  return (ushort_t)(r >> 16);
}
__device__ __forceinline__ float bf2f(ushort_t u) {
  union { unsigned int u; float f; } v; v.u = ((unsigned int)u) << 16;
  return v.f;
}

// async global->LDS, 16B/lane; LDS dest = wave-uniform base + lane*16
typedef __attribute__((address_space(1))) const unsigned int as1_uint;
typedef __attribute__((address_space(3))) unsigned int as3_uint;
__device__ __forceinline__ void gl_lds16(const ushort_t* g, ushort_t* l) {
  __builtin_amdgcn_global_load_lds((as1_uint*)g, (as3_uint*)l, 16, 0, 0);
}

// ---------------------------------------------------------------------------
// Fused prep: converts (img, topic) + 7 weight transposes (validated R18/R19).
// ---------------------------------------------------------------------------
__device__ __forceinline__ void trans_tile(
    const float* __restrict__ in, ushort_t* __restrict__ out,
    int r0, int R, int C, int Rp, int Cp, int bx, int by)
{
  __shared__ float tile[64][65];
  const int t = threadIdx.x;
  const int lc = t & 63, g = t >> 6;
  const int rbase = by * 64, cbase = bx * 64;
#pragma unroll
  for (int i = 0; i < 16; ++i) {
    int lr = g + 4 * i;
    int rr = rbase + lr, cc = cbase + lc;
    tile[lr][lc] = (rr < R && cc < C) ? in[(size_t)(r0 + rr) * C + cc] : 0.f;
  }
  __syncthreads();
#pragma unroll
  for (int i = 0; i < 16; ++i) {
    int wr2 = g + 4 * i;
    int oc = cbase + wr2, orr = rbase + lc;
    if (oc < Cp && orr < Rp)
      out[(size_t)oc * Rp + orr] = f2bf(tile[lc][wr2]);
  }
}

#define CONV_NB_IMG  2304
#define CONV_NB_TOP  4000
#define CONV_TOTAL   6304
#define TJ1_OFF 0
#define TJ2_OFF 256
#define TJ3_OFF 512
#define TJ4_OFF 592
#define TJ5_OFF 672
#define TJ6_OFF 2016
#define TJ7_OFF 2456
#define TJ_TOTAL 3800
#define PREP_TOTAL (CONV_TOTAL + TJ_TOTAL)

__global__ __launch_bounds__(256) void prep_all_k(
    const float* __restrict__ img, ushort_t* __restrict__ img_bf,
    const float* __restrict__ topic, ushort_t* __restrict__ topic_bf,
    const float* __restrict__ Wy_img, ushort_t* __restrict__ WyT_img,
    const float* __restrict__ Wg_img, ushort_t* __restrict__ WgT_img,
    const float* __restrict__ Wy_t,  ushort_t* __restrict__ WyT_t,
    const float* __restrict__ Wg_t,  ushort_t* __restrict__ WgT_t,
    const float* __restrict__ W1,    ushort_t* __restrict__ W1T_top,
    ushort_t* __restrict__ W1T_bot,
    const float* __restrict__ W2,    ushort_t* __restrict__ W2T)
{
  const int bid0 = blockIdx.x;
  if (bid0 < CONV_NB_IMG) {
    int i = bid0 * 256 + threadIdx.x;
    float4 v = reinterpret_cast<const float4*>(img)[i];
    ushort4 o;
    o.x = f2bf(v.x); o.y = f2bf(v.y); o.z = f2bf(v.z); o.w = f2bf(v.w);
    reinterpret_cast<ushort4*>(img_bf)[i] = o;
    return;
  }
  if (bid0 < CONV_TOTAL) {
    const int npc = TDIMP_ >> 2;
    int i = (bid0 - CONV_NB_IMG) * 256 + threadIdx.x;
    int row = i / npc, c4 = (i - row * npc) << 2;
    ushort4 o = make_ushort4(0, 0, 0, 0);
    if (c4 < TDIM_) {
      float4 v = *reinterpret_cast<const float4*>(&topic[(size_t)row * TDIM_ + c4]);
      o.x = f2bf(v.x); o.y = f2bf(v.y); o.z = f2bf(v.z); o.w = f2bf(v.w);
    }
    *reinterpret_cast<ushort4*>(&topic_bf[(size_t)row * TDIMP_ + c4]) = o;
    return;
  }
  const int bid = bid0 - CONV_TOTAL;
  if (bid < TJ2_OFF) {
    int l = bid - TJ1_OFF;
    trans_tile(Wy_img, WyT_img, 0, 2048, 512, 2048, 512, l % 8, l / 8);
  } else if (bid < TJ3_OFF) {
    int l = bid - TJ2_OFF;
    trans_tile(Wg_img, WgT_img, 0, 2048, 512, 2048, 512, l % 8, l / 8);
  } else if (bid < TJ4_OFF) {
    int l = bid - TJ3_OFF;
    trans_tile(Wy_t, WyT_t, 0, 600, 512, TDIMP_, 512, l % 8, l / 8);
  } else if (bid < TJ5_OFF) {
    int l = bid - TJ4_OFF;
    trans_tile(Wg_t, WgT_t, 0, 600, 512, TDIMP_, 512, l % 8, l / 8);
  } else if (bid < TJ6_OFF) {
    int l = bid - TJ5_OFF;
    trans_tile(W1, W1T_top, 0, 2048, CAT_, 2048, CATP_R, l % 42, l / 42);
  } else if (bid < TJ7_OFF) {
    int l = bid - TJ6_OFF;
    trans_tile(W1, W1T_bot, 2048, 600, CAT_, TDIMP_, CATP_R8, l % 44, l / 44);
  } else {
    int l = bid - TJ7_OFF;
    trans_tile(W2, W2T, 0, CAT_, 2048, CATP_K, 2048, l % 32, l / 32);
  }
}

// ---------------------------------------------------------------------------
// mid_all_k: fused {gated img, gated topic, himg 128^2 GEMM} (validated R19).
// ---------------------------------------------------------------------------
__device__ __forceinline__ void gated_body(
    ushort_t* __restrict__ smem,
    const ushort_t* __restrict__ A,
    const ushort_t* __restrict__ ByT, const ushort_t* __restrict__ BgT,
    const float* __restrict__ by, const float* __restrict__ bg,
    ushort_t* __restrict__ out, int M, int Kp, int bx, int byi)
{
  ushort_t* Als = smem;
  ushort_t* Bls = smem + 8192;
  const int tid = threadIdx.x;
  const int lane = tid & 63, w = tid >> 6;
  const int wr = w >> 1, wc = w & 1;
  const int m0 = byi * 128, n0 = bx * 64;
  const int N = LSTM_;

  const int srow = lane >> 2;
  const int scol = (lane & 3) * 8;
  const ushort_t* gA0 = A + (size_t)(m0 + w * 32 + srow) * Kp + scol;
  const ushort_t* gA1 = gA0 + (size_t)16 * Kp;
  const ushort_t* gBm = (w >> 1) ? BgT : ByT;
  const ushort_t* gB0 = gBm + (size_t)(n0 + (w & 1) * 32 + srow) * Kp + scol;
  const ushort_t* gB1 = gB0 + (size_t)16 * Kp;
  const int dA0 = (w * 32) * 32, dA1 = (w * 32 + 16) * 32;
  const int dB0 = ((w & 1) * 32) * 32, dB1 = ((w & 1) * 32 + 16) * 32;
  const int bm = w >> 1;

#define STAGE_W(BUF, KOFF) do {                                   \
    gl_lds16(gA0 + (KOFF), Als + (BUF) * 4096 + dA0);             \
    gl_lds16(gA1 + (KOFF), Als + (BUF) * 4096 + dA1);             \
    gl_lds16(gB0 + (KOFF), Bls + (BUF) * 4096 + bm * 2048 + dB0); \
    gl_lds16(gB1 + (KOFF), Bls + (BUF) * 4096 + bm * 2048 + dB1); \
  } while (0)

  f32x4 accy[4][2] = {}, accg[4][2] = {};
  short8 af[4], byf[2], bgf[2];

#define GATED_COMP(BUF) do {                                                  \
    _Pragma("unroll")                                                         \
    for (int i = 0; i < 4; ++i)                                               \
      af[i] = *reinterpret_cast<const short8*>(                               \
          Als + (BUF) * 4096 +                                                \
          (wr * 64 + i * 16 + (lane & 15)) * 32 + (lane >> 4) * 8);           \
    _Pragma("unroll")                                                         \
    for (int j = 0; j < 2; ++j) {                                             \
      int boff = (wc * 32 + j * 16 + (lane & 15)) * 32 + (lane >> 4) * 8;     \
      byf[j] = *reinterpret_cast<const short8*>(Bls + (BUF) * 4096 + boff);   \
      bgf[j] = *reinterpret_cast<const short8*>(Bls + (BUF) * 4096 + 2048 + boff); \
    }                                                                         \
    _Pragma("unroll")                                                         \
    for (int i = 0; i < 4; ++i)                                               \
      _Pragma("unroll")                                                       \
      for (int j = 0; j < 2; ++j) {                                           \
        accy[i][j] = __builtin_amdgcn_mfma_f32_16x16x32_bf16(af[i], byf[j], accy[i][j], 0, 0, 0); \
        accg[i][j] = __builtin_amdgcn_mfma_f32_16x16x32_bf16(af[i], bgf[j], accg[i][j], 0, 0, 0); \
      }                                                                       \
  } while (0)

  STAGE_W(0, 0);
  __syncthreads();
  int kb = 0;
  const int nt2 = Kp >> 6;
  for (int i = 0; i < nt2 - 1; ++i) {
    STAGE_W(1, kb + 32);
    GATED_COMP(0);
    __syncthreads();
    STAGE_W(0, kb + 64);
    GATED_COMP(1);
    __syncthreads();
    kb += 64;
  }
  STAGE_W(1, kb + 32);
  GATED_COMP(0);
  __syncthreads();
  GATED_COMP(1);
#undef STAGE_W
#undef GATED_COMP

  const int crow = (lane >> 4) * 4, ccol = lane & 15;
#pragma unroll
  for (int i = 0; i < 4; ++i)
#pragma unroll
    for (int j = 0; j < 2; ++j)
#pragma unroll
      for (int q = 0; q < 4; ++q) {
        int gm = m0 + wr * 64 + i * 16 + crow + q;
        int gn = n0 + wc * 32 + j * 16 + ccol;
        if (gm >= M || gn >= N) continue;
        float y = tanhf(accy[i][j][q] + by[gn]);
        float g = accg[i][j][q] + bg[gn];
        g = (g > 0.f) ? g : 0.01f * g;
        out[(size_t)gm * N + gn] = f2bf(y * g);
      }
}

__device__ __forceinline__ void gemm128_body(
    ushort_t* __restrict__ smem,
    const ushort_t* __restrict__ A, const ushort_t* __restrict__ BT,
    float* __restrict__ outf, int M, int Kp, int N, int bx, int by)
{
  ushort_t* Als = smem;
  ushort_t* Bls = smem + 8192;
  const int tid = threadIdx.x;
  const int lane = tid & 63, w = tid >> 6;
  const int wr = w >> 1, wc = w & 1;
  const int m0 = by * 128, n0 = bx * 128;

  const int srow = lane >> 2;
  const int scol = (lane & 3) * 8;
  const ushort_t* gA0 = A + (size_t)(m0 + w * 32 + srow) * Kp + scol;
  const ushort_t* gA1 = gA0 + (size_t)16 * Kp;
  const ushort_t* gB0 = BT + (size_t)(n0 + w * 32 + srow) * Kp + scol;
  const ushort_t* gB1 = gB0 + (size_t)16 * Kp;
  const int d0 = (w * 32) * 32, d1 = (w * 32 + 16) * 32;

#define STAGE_G(BUF, KOFF) do {                           \
    gl_lds16(gA0 + (KOFF), Als + (BUF) * 4096 + d0);      \
    gl_lds16(gA1 + (KOFF), Als + (BUF) * 4096 + d1);      \
    gl_lds16(gB0 + (KOFF), Bls + (BUF) * 4096 + d0);      \
    gl_lds16(gB1 + (KOFF), Bls + (BUF) * 4096 + d1);      \
  } while (0)

  f32x4 acc[4][4] = {};
  short8 af[4], bfv[4];

#define GEMM_COMP(BUF) do {                                                   \
    _Pragma("unroll")                                                         \
    for (int i = 0; i < 4; ++i)                                               \
      af[i] = *reinterpret_cast<const short8*>(                               \
          Als + (BUF) * 4096 +                                                \
          (wr * 64 + i * 16 + (lane & 15)) * 32 + (lane >> 4) * 8);           \
    _Pragma("unroll")                                                         \
    for (int j = 0; j < 4; ++j)                                               \
      bfv[j] = *reinterpret_cast<const short8*>(                              \
          Bls + (BUF) * 4096 +                                                \
          (wc * 64 + j * 16 + (lane & 15)) * 32 + (lane >> 4) * 8);           \
    _Pragma("unroll")                                                         \
    for (int i = 0; i < 4; ++i)                                               \
      _Pragma("unroll")                                                       \
      for (int j = 0; j < 4; ++j)                                             \
        acc[i][j] = __builtin_amdgcn_mfma_f32_16x16x32_bf16(af[i], bfv[j], acc[i][j], 0, 0, 0); \
  } while (0)

  STAGE_G(0, 0);
  __syncthreads();
  int kb = 0;
  const int nt2 = Kp >> 6;
  for (int i = 0; i < nt2 - 1; ++i) {
    STAGE_G(1, kb + 32);
    GEMM_COMP(0);
    __syncthreads();
    STAGE_G(0, kb + 64);
    GEMM_COMP(1);
    __syncthreads();
    kb += 64;
  }
  STAGE_G(1, kb + 32);
  GEMM_COMP(0);
  __syncthreads();
  GEMM_COMP(1);
#undef STAGE_G
#undef GEMM_COMP

  const int crow = (lane >> 4) * 4, ccol = lane & 15;
#pragma unroll
  for (int i = 0; i < 4; ++i)
#pragma unroll
    for (int j = 0; j < 4; ++j)
#pragma unroll
      for (int q = 0; q < 4; ++q) {
        int gm = m0 + wr * 64 + i * 16 + crow + q;
        int gn = n0 + wc * 64 + j * 16 + ccol;
        if (gm < M && gn < N) outf[(size_t)gm * N + gn] = acc[i][j][q];
      }
}

#define GB_IMG 72
#define GB_TOP 400
#define HB_NB  189
#define MID_TOTAL (GB_IMG + GB_TOP + HB_NB)

__global__ __launch_bounds__(256) void mid_all_k(
    const ushort_t* __restrict__ img_bf,
    const ushort_t* __restrict__ WyT_img, const ushort_t* __restrict__ WgT_img,
    const float* __restrict__ by_img, const float* __restrict__ bg_img,
    ushort_t* __restrict__ v_feat,
    const ushort_t* __restrict__ topic_bf,
    const ushort_t* __restrict__ WyT_t, const ushort_t* __restrict__ WgT_t,
    const float* __restrict__ by_t, const float* __restrict__ bg_t,
    ushort_t* __restrict__ topic_ft,
    const ushort_t* __restrict__ W1T_top, float* __restrict__ himg)
{
  __shared__ ushort_t smem[16384];
  const int bid = blockIdx.x;
  if (bid < GB_IMG) {
    gated_body(smem, img_bf, WyT_img, WgT_img, by_img, bg_img, v_feat,
               1152, 2048, bid & 7, bid >> 3);
  } else if (bid < GB_IMG + GB_TOP) {
    const int l = bid - GB_IMG;
    gated_body(smem, topic_bf, WyT_t, WgT_t, by_t, bg_t, topic_ft,
               6400, TDIMP_, l & 7, l >> 3);
  } else {
    const int l = bid - GB_IMG - GB_TOP;
    gemm128_body(smem, img_bf, W1T_top, himg, 1152, 2048, CAT_,
                 l % 21, l / 21);
  }
}

// ---------------------------------------------------------------------------
// gemm128e_k: E on the 128^2 2-phase kernel (R7-R9 validated mode-1 path).
// 32 KB LDS -> multiple blocks/CU (TLP hides latency for short K=640).
// Merged both chunks: 2 x (21 bx x 45 by) = 1890 blocks.
// Epilogue: h1 = bf16(relu(acc + himg[dmap(base+gm)] + b1)), pad cols zeroed.
// ---------------------------------------------------------------------------
#define E128_PER 945
__global__ __launch_bounds__(256) void gemm128e_k(
    const ushort_t* __restrict__ vt, const ushort_t* __restrict__ BT,
    const float* __restrict__ bias, const float* __restrict__ D,
    ushort_t* __restrict__ h1c0, ushort_t* __restrict__ h1c1)
{
  __shared__ ushort_t Als[2][128 * 32];
  __shared__ ushort_t Bls[2][128 * 32];
  const int c = blockIdx.x < E128_PER ? 0 : 1;
  const int l = blockIdx.x - c * E128_PER;
  const int bx = l % 21, by = l / 21;
  const ushort_t* A = vt + (size_t)c * 5760 * TDIMP_;
  ushort_t* outb = c ? h1c1 : h1c0;
  const int base = c * 5760;
  const int Kp = TDIMP_;                 // 640, nt2 = 10

  const int tid = threadIdx.x;
  const int lane = tid & 63, w = tid >> 6;
  const int wr = w >> 1, wc = w & 1;
  const int m0 = by * 128, n0 = bx * 128;

  const int srow = lane >> 2;
  const int scol = (lane & 3) * 8;
  const ushort_t* gA0 = A + (size_t)(m0 + w * 32 + srow) * Kp + scol;
  const ushort_t* gA1 = gA0 + (size_t)16 * Kp;
  const ushort_t* gB0 = BT + (size_t)(n0 + w * 32 + srow) * Kp + scol;
  const ushort_t* gB1 = gB0 + (size_t)16 * Kp;
  const int d0 = (w * 32) * 32, d1 = (w * 32 + 16) * 32;

#define STAGE_E(BUF, KOFF) do {                      \
    gl_lds16(gA0 + (KOFF), &Als[BUF][d0]);           \
    gl_lds16(gA1 + (KOFF), &Als[BUF][d1]);           \
    gl_lds16(gB0 + (KOFF), &Bls[BUF][d0]);           \
    gl_lds16(gB1 + (KOFF), &Bls[BUF][d1]);           \
  } while (0)

  f32x4 acc[4][4] = {};
  short8 af[4], bfv[4];

#define COMP_E(BUF) do {                                                      \
    _Pragma("unroll")                                                         \
    for (int i = 0; i < 4; ++i)                                               \
      af[i] = *reinterpret_cast<const short8*>(                               \
          &Als[BUF][(wr * 64 + i * 16 + (lane & 15)) * 32 + (lane >> 4) * 8]);\
    _Pragma("unroll")                                                         \
    for (int j = 0; j < 4; ++j)                                               \
      bfv[j] = *reinterpret_cast<const short8*>(                              \
          &Bls[BUF][(wc * 64 + j * 16 + (lane & 15)) * 32 + (lane >> 4) * 8]);\
    _Pragma("unroll")                                                         \
    for (int i = 0; i < 4; ++i)                                               \
      _Pragma("unroll")                                                       \
      for (int j = 0; j < 4; ++j)                                             \
        acc[i][j] = __builtin_amdgcn_mfma_f32_16x16x32_bf16(af[i], bfv[j], acc[i][j], 0, 0, 0); \
  } while (0)

  STAGE_E(0, 0);
  __syncthreads();
  int kb = 0;
  const int nt2 = Kp >> 6;
  for (int i = 0; i < nt2 - 1; ++i) {
    STAGE_E(1, kb + 32);
    COMP_E(0);
    __syncthreads();
    STAGE_E(0, kb + 64);
    COMP_E(1);
    __syncthreads();
    kb += 64;
  }
  STAGE_E(1, kb + 32);
  COMP_E(0);
  __syncthreads();
  COMP_E(1);
#undef STAGE_E
#undef COMP_E

  // mode-1 epilogue (R7-R9 validated): dmap D-add, bias, relu, bf16, pad-zero
  const int crow = (lane >> 4) * 4, ccol = lane & 15;
#pragma unroll
  for (int i = 0; i < 4; ++i)
#pragma unroll
    for (int j = 0; j < 4; ++j)
#pragma unroll
      for (int q = 0; q < 4; ++q) {
        int gm = m0 + wr * 64 + i * 16 + crow + q;
        int gn = n0 + wc * 64 + j * 16 + ccol;
        float vv = 0.f;
        if (gn < CAT_) {
          int g = base + gm;
          int drow = (g / 360) * 36 + (g % 36);
          vv = acc[i][j][q] + D[(size_t)drow * CAT_ + gn] + bias[gn];
          vv = vv > 0.f ? vv : 0.f;
        }
        outb[(size_t)gm * CATP_K + gn] = f2bf(vv);
      }
}

// ---------------------------------------------------------------------------
// 8-phase 256-wide GEMM body, v3 schedule (validated R12..R25), templated on
// MF = M-fragments per wave (BM = MF*32).
// ---------------------------------------------------------------------------
template<int MF>
__device__ __forceinline__ void gemm8_body(
    ushort_t* __restrict__ lds8, int bx, int by,
    const ushort_t* __restrict__ A, const ushort_t* __restrict__ BT,
    const float* __restrict__ bias, const float* __restrict__ D,
    float* __restrict__ outf, ushort_t* __restrict__ outb,
    int M, int Kp, int N, int ldOutb, int mode, int base)
{
  const int tid = threadIdx.x;
  const int lane = tid & 63, w = tid >> 6;
  const int wr = w >> 2, wc = w & 3;     // 2M x 4N waves
  const int m0 = by * (MF * 32), n0 = bx * 256;
  const int r15 = lane & 15, lg = lane >> 4;

  // staging source coords (inverse-swizzled)
  const int pr = lane >> 3, hh = lane & 7;
  const int cc = hh ^ pr;
  const int srow_l = (pr << 1) | (cc >> 2);
  const int scol_l = (cc & 3) << 3;

#define STAGE8(b_, s_, kt_) do {                                             \
    const ushort_t* src_ = ((s_) & 1) ? BT : A;                              \
    const int rowb_ = ((s_) & 1) ? n0 : m0;                                  \
    const int kcol_ = (kt_) * 64 + ((s_) >> 1) * 32 + scol_l;                \
    ushort_t* dst_ = &lds8[(b_) * 32768 + (s_) * 8192];                      \
    _Pragma("unroll")                                                        \
    for (int i_ = 0; i_ < 2; ++i_) {                                         \
      int grow_ = rowb_ + w * 32 + i_ * 16 + srow_l;                         \
      gl_lds16(src_ + (size_t)grow_ * Kp + kcol_,                            \
               &dst_[(w * 32 + i_ * 16) * 32]);                              \
    }                                                                        \
  } while (0)

#define LDS_RD(b_, s_, row_) (*reinterpret_cast<const short8*>(              \
    &lds8[(b_) * 32768 + (s_) * 8192 + ((row_) >> 1) * 64 +                  \
          (((((row_) & 1) << 2) | lg) ^ (((row_) >> 1) & 7)) * 8]))

  f32x4 acc[MF][4] = {};
  short8 aR0[MF], aR1[MF];
  short8 bR0[2], bR1[2];
  const int NT = Kp >> 6;

#define PHASE_WAIT() do {                                   \
    asm volatile("s_waitcnt vmcnt(4)" ::: "memory");        \
    __builtin_amdgcn_s_barrier();                           \
    __builtin_amdgcn_sched_barrier(0);                      \
  } while (0)

#define PRELOAD_A(ar_, b_, ks_) do {                                        \
    _Pragma("unroll")                                                       \
    for (int mf_ = 0; mf_ < MF; ++mf_)                                      \
      ar_[mf_] = LDS_RD(b_, (ks_) * 2, wr * (MF * 16) + mf_ * 16 + r15);    \
  } while (0)

#define PRELOAD_B(br_, b_, ks_, nfb_) do {                                  \
    br_[0] = LDS_RD(b_, (ks_) * 2 + 1, wc * 64 + (nfb_) * 16 + r15);        \
    br_[1] = LDS_RD(b_, (ks_) * 2 + 1, wc * 64 + ((nfb_) + 1) * 16 + r15);  \
  } while (0)

#define MFMA_G(ar_, br_, nfb_) do {                                         \
    __builtin_amdgcn_sched_barrier(0);                                      \
    __builtin_amdgcn_s_setprio(1);                                          \
    _Pragma("unroll")                                                       \
    for (int mf_ = 0; mf_ < MF; ++mf_) {                                    \
      acc[mf_][(nfb_)] = __builtin_amdgcn_mfma_f32_16x16x32_bf16(           \
          ar_[mf_], br_[0], acc[mf_][(nfb_)], 0, 0, 0);                     \
      acc[mf_][(nfb_) + 1] = __builtin_amdgcn_mfma_f32_16x16x32_bf16(       \
          ar_[mf_], br_[1], acc[mf_][(nfb_) + 1], 0, 0, 0);                 \
    }                                                                       \
    __builtin_amdgcn_s_setprio(0);                                          \
    __builtin_amdgcn_sched_barrier(0);                                      \
  } while (0)

  // prologue: stage tile 0 into buf 0; drain; preload phase-0 regs
  STAGE8(0, 0, 0); STAGE8(0, 1, 0); STAGE8(0, 2, 0); STAGE8(0, 3, 0);
  asm volatile("s_waitcnt vmcnt(0)" ::: "memory");
  __builtin_amdgcn_s_barrier();
  __builtin_amdgcn_sched_barrier(0);
  PRELOAD_A(aR0, 0, 0);
  PRELOAD_B(bR0, 0, 0, 0);

  for (int T = 0; T < NT - 1; ++T) {
    const int b = T & 1, nb = b ^ 1;
    STAGE8(nb, 0, T + 1);
    PHASE_WAIT();
    PRELOAD_B(bR1, b, 0, 2);
    MFMA_G(aR0, bR0, 0);
    STAGE8(nb, 1, T + 1);
    PHASE_WAIT();
    PRELOAD_A(aR1, b, 1);
    PRELOAD_B(bR0, b, 1, 0);
    MFMA_G(aR0, bR1, 2);
    STAGE8(nb, 2, T + 1);
    PHASE_WAIT();
    PRELOAD_B(bR1, b, 1, 2);
    MFMA_G(aR1, bR0, 0);
    STAGE8(nb, 3, T + 1);
    PHASE_WAIT();
    PRELOAD_A(aR0, nb, 0);
    PRELOAD_B(bR0, nb, 0, 0);
    MFMA_G(aR1, bR1, 2);
  }
  {
    asm volatile("s_waitcnt vmcnt(0)" ::: "memory");
    __builtin_amdgcn_s_barrier();
    __builtin_amdgcn_sched_barrier(0);
    const int b = (NT - 1) & 1;
    PRELOAD_B(bR1, b, 0, 2);
    MFMA_G(aR0, bR0, 0);
    PRELOAD_A(aR1, b, 1);
    PRELOAD_B(bR0, b, 1, 0);
    MFMA_G(aR0, bR1, 2);
    PRELOAD_B(bR1, b, 1, 2);
    MFMA_G(aR1, bR0, 0);
    MFMA_G(aR1, bR1, 2);
  }
#undef STAGE8
#undef PHASE_WAIT
#undef PRELOAD_A
#undef PRELOAD_B
#undef MFMA_G
#undef LDS_RD

  // epilogue write: C/D frag layout col=lane&15, row=(lane>>4)*4+q
  const int crow = lg * 4;
#pragma unroll
  for (int mf = 0; mf < MF; ++mf) {
#pragma unroll
    for (int nf = 0; nf < 4; ++nf) {
#pragma unroll
      for (int q = 0; q < 4; ++q) {
        int gm = m0 + wr * (MF * 16) + mf * 16 + crow + q;
        int gn = n0 + wc * 64 + nf * 16 + r15;
        if (gm >= M) continue;
        float v = acc[mf][nf][q];
        if (mode == 1) {
          if (gn < ldOutb) {
            float vv = 0.f;
            if (gn < N) {
              int g = base + gm;
              int drow = (g / 360) * 36 + (g % 36);
              vv = v + D[(size_t)drow * CAT_ + gn] + bias[gn];
              vv = vv > 0.f ? vv : 0.f;
            }
            outb[(size_t)gm * ldOutb + gn] = f2bf(vv);
          }
        } else {
          if (gn < N) {
            float vv = v + bias[gn];
            outf[(size_t)gm * N + gn] = vv > 0.f ? vv : 0.f;
          }
        }
      }
    }
  }
}

// E launch, single chunk 8-phase (R23-validated fallback path).
#define E_NB 253   // 11 bx x 23 by
__global__ __launch_bounds__(512, 2) void mfma_gemm8_eswz_k(
    const ushort_t* __restrict__ A, const ushort_t* __restrict__ BT,
    const float* __restrict__ bias, const float* __restrict__ D,
    ushort_t* __restrict__ outb, int base)
{
  extern __shared__ ushort_t lds8[];
  const int bid = blockIdx.x;
  const int xcd = bid & 7, j = bid >> 3;
  const int wgid = (xcd < 5 ? xcd * 32 : 160 + (xcd - 5) * 31) + j;
  const int bx = wgid % 11, by = wgid / 11;
  gemm8_body<8>(lds8, bx, by, A, BT, bias, D, nullptr, outb,
                5760, TDIMP_, CAT_, CATP_K, 1, base);
}

// F launch at BM=192 (MF=6), validated R25: 240 blocks, T1 swizzle.
#define F192_NB 240
__global__ __launch_bounds__(512, 2) void mfma_gemm8_f192_k(
    const ushort_t* __restrict__ h1, const ushort_t* __restrict__ W2T,
    const float* __restrict__ b2, float* __restrict__ outf)
{
  extern __shared__ ushort_t lds8[];
  const int bid = blockIdx.x;
  const int swz = (bid & 7) * 30 + (bid >> 3);   // bijective on [0,240)
  const int bx = swz & 7, by = swz >> 3;
  gemm8_body<6>(lds8, bx, by, h1, W2T, b2, nullptr, outf, nullptr,
                5760, CATP_K, 2048, 0, 2, 0);
}

// ---------------------------------------------------------------------------
// Fused attention v2 (validated R20): short8 score loads.
// ---------------------------------------------------------------------------
__global__ __launch_bounds__(256) void attn_fuse_k(
    const ushort_t* __restrict__ v_feat,
    const ushort_t* __restrict__ topic_feat,
    const float* __restrict__ topic_raw,
    const int*   __restrict__ qnp,
    ushort_t* __restrict__ vt_att)
{
  const int b  = blockIdx.x;
  const int ib = b / NUM_R_;
  __shared__ float tr[SL_Q_][TDIM_];
  __shared__ float msk[SL_Q_];

  const int tid = threadIdx.x;
  {
    const float4* g = reinterpret_cast<const float4*>(topic_raw + (size_t)b * SL_Q_ * TDIM_);
    float4* s = reinterpret_cast<float4*>(&tr[0][0]);
    for (int i = tid; i < SL_Q_ * TDIM_ / 4; i += 256) s[i] = g[i];
  }
  if (tid < SL_Q_) msk[tid] = (float)qnp[b * SL_Q_ + tid];
  __syncthreads();

  const int wave = tid >> 6, lane = tid & 63;
  const ushort_t* tf_b = topic_feat + (size_t)b * SL_Q_ * LSTM_;

  for (int p = wave; p < NUM_P_; p += 4) {
    const ushort_t* v = v_feat + ((size_t)ib * NUM_P_ + p) * LSTM_;
    float vr[8];
    {
      short8 vv = *reinterpret_cast<const short8*>(&v[lane * 8]);
#pragma unroll
      for (int k = 0; k < 8; ++k) vr[k] = bf2f((ushort_t)vv[k]);
    }

    float sc[SL_Q_];
#pragma unroll
    for (int s = 0; s < SL_Q_; ++s) {
      short8 tv = *reinterpret_cast<const short8*>(&tf_b[(size_t)s * LSTM_ + lane * 8]);
      float acc = 0.f;
#pragma unroll
      for (int k = 0; k < 8; ++k) acc += vr[k] * bf2f((ushort_t)tv[k]);
#pragma unroll
      for (int off = 32; off > 0; off >>= 1) acc += __shfl_xor(acc, off, 64);
      sc[s] = acc;
    }
    float mx = -1e30f;
#pragma unroll
    for (int s = 0; s < SL_Q_; ++s) {
      float m = msk[s];
      sc[s] = sc[s] * m + (m - 1.f) * 10000.f;
      mx = fmaxf(mx, sc[s]);
    }
    float sum = 0.f;
#pragma unroll
    for (int s = 0; s < SL_Q_; ++s) { sc[s] = expf(sc[s] - mx); sum += sc[s]; }
    const float inv = 1.f / sum;

    ushort_t* outp = vt_att + ((size_t)b * NUM_P_ + p) * TDIMP_;
    for (int t = lane; t < TDIMP_; t += 64) {
      float acc = 0.f;
      if (t < TDIM_) {
#pragma unroll
        for (int s = 0; s < SL_Q_; ++s) acc += sc[s] * tr[s][t];
        acc *= inv;
      }
      outp[t] = f2bf(t < TDIM_ ? acc : 0.f);
    }
  }
}

// ---------------------------------------------------------------------------
extern "C" void kernel_launch(void* const* d_in, const int* in_sizes, int n_in,
                              void* d_out, int out_size, void* d_ws, size_t ws_size,
                              hipStream_t stream) {
  const float* img    = (const float*)d_in[0];
  const float* topic  = (const float*)d_in[1];
  const int*   qnp    = (const int*)d_in[2];
  const float* Wy_img = (const float*)d_in[3];
  const float* by_img = (const float*)d_in[4];
  const float* Wg_img = (const float*)d_in[5];
  const float* bg_img = (const float*)d_in[6];
  const float* Wy_t   = (const float*)d_in[7];
  const float* by_t   = (const float*)d_in[8];
  const float* Wg_t   = (const float*)d_in[9];
  const float* bg_t   = (const float*)d_in[10];
  const float* W1     = (const float*)d_in[11];
  const float* b1     = (const float*)d_in[12];
  const float* W2     = (const float*)d_in[13];
  const float* b2     = (const float*)d_in[14];
  float* out = (float*)d_out;

  // --- workspace ---
  char* base = (char*)d_ws;
  size_t off = 0;
  auto alloc = [&](size_t bytes) {
    void* p = base + off;
    off += (bytes + 255) & ~(size_t)255;
    return p;
  };
  // region X (~37.2 MB): dead after mid phase; h1c0 (31.7 MB) aliases it
  ushort_t* img_bf    = (ushort_t*)alloc((size_t)1152 * 2048 * 2);
  ushort_t* topic_bf  = (ushort_t*)alloc((size_t)6400 * TDIMP_ * 2);
  ushort_t* WyT_img   = (ushort_t*)alloc((size_t)512 * 2048 * 2);
  ushort_t* WgT_img   = (ushort_t*)alloc((size_t)512 * 2048 * 2);
  ushort_t* WyT_t     = (ushort_t*)alloc((size_t)512 * TDIMP_ * 2);
  ushort_t* WgT_t     = (ushort_t*)alloc((size_t)512 * TDIMP_ * 2);
  ushort_t* W1T_top   = (ushort_t*)alloc((size_t)CATP_R * 2048 * 2);
  ushort_t* v_feat    = (ushort_t*)alloc((size_t)1152 * 512 * 2);
  ushort_t* topic_ft  = (ushort_t*)alloc((size_t)6400 * 512 * 2);
  // persistent
  ushort_t* W1T_bot   = (ushort_t*)alloc((size_t)CATP_R8 * TDIMP_ * 2);
  ushort_t* W2T       = (ushort_t*)alloc((size_t)2048 * CATP_K * 2);
  ushort_t* vt_att    = (ushort_t*)alloc((size_t)(11520 + 128) * TDIMP_ * 2);
  float*    himg      = (float*)alloc((size_t)1152 * CAT_ * 4);
  // second h1 chunk (31.7 MB) for the merged-E path (ws >= 110.6MB proven R21)
  ushort_t* h1c1      = (ushort_t*)alloc((size_t)5888 * CATP_K * 2);
  const bool merged   = (ws_size >= off);
  ushort_t* h1c0      = (ushort_t*)base;   // aliases region X (5888 x 2688)

  const dim3 blk(256);

  // --- phase A: fused prep ---
  prep_all_k<<<dim3(PREP_TOTAL), blk, 0, stream>>>(
      img, img_bf, topic, topic_bf,
      Wy_img, WyT_img, Wg_img, WgT_img, Wy_t, WyT_t, Wg_t, WgT_t,
      W1, W1T_top, W1T_bot, W2, W2T);

  // --- phase B: fused gated + himg ---
  mid_all_k<<<dim3(MID_TOTAL), blk, 0, stream>>>(
      img_bf, WyT_img, WgT_img, by_img, bg_img, v_feat,
      topic_bf, WyT_t, WgT_t, by_t, bg_t, topic_ft,
      W1T_top, himg);

  // --- phase C: attention ---
  attn_fuse_k<<<dim3(BS_ * NUM_R_), blk, 0, stream>>>(v_feat, topic_ft, topic, qnp, vt_att);

  if (merged) {
    // merged E on 128^2 2-phase kernel (1890 blocks, ~5 blocks/CU TLP),
    // then two full-fill F-192 rounds (240 each)
    gemm128e_k<<<dim3(2 * E128_PER), blk, 0, stream>>>(
        vt_att, W1T_bot, b1, himg, h1c0, h1c1);
    mfma_gemm8_f192_k<<<dim3(F192_NB), dim3(512), 131072, stream>>>(
        h1c0, W2T, b2, out);
    mfma_gemm8_f192_k<<<dim3(F192_NB), dim3(512), 131072, stream>>>(
        h1c1, W2T, b2, out + (size_t)5760 * IMG_F_);
  } else {
    // fallback: sequential chunks with single h1c0 (validated class)
    for (int c = 0; c < 2; ++c) {
      const int mbase = c * 5760;
      mfma_gemm8_eswz_k<<<dim3(E_NB), dim3(512), 131072, stream>>>(
          vt_att + (size_t)mbase * TDIMP_, W1T_bot, b1, himg, h1c0, mbase);
      mfma_gemm8_f192_k<<<dim3(F192_NB), dim3(512), 131072, stream>>>(
          h1c0, W2T, b2, out + (size_t)mbase * IMG_F_);
    }
  }
}

// Round 27
// 405.110 us; speedup vs baseline: 1.0311x; 1.0311x over previous
//
#include <hip/hip_runtime.h>
#include <hip/hip_bf16.h>
#include <cstddef>
#include <cstdint>

#define BS_     32
#define NUM_R_  10
#define NUM_P_  36
#define SL_Q_   20
#define IMG_F_  2048
#define TDIM_   600
#define TDIMP_  640     // 600 padded to %64==0
#define LSTM_   512
#define CAT_    2648
#define CATP_K  2688    // 2648 padded to %64==0 (42 x 64)
#define CATP_R  2688    // B-row pad for 128-tiles (himg)
#define CATP_R8 2816    // B-row pad for 256-tiles (11 x 256, mode-1)

typedef unsigned short ushort_t;
typedef __attribute__((ext_vector_type(8))) short short8;
typedef __attribute__((ext_vector_type(4))) float f32x4;

__device__ __forceinline__ ushort_t f2bf(float f) {
  union { float f; unsigned int u; } v; v.f = f;
  unsigned int r = v.u + 0x7fff + ((v.u >> 16) & 1);
  return (ushort_t)(r >> 16);
}
__device__ __forceinline__ float bf2f(ushort_t u) {
  union { unsigned int u; float f; } v; v.u = ((unsigned int)u) << 16;
  return v.f;
}

// async global->LDS, 16B/lane; LDS dest = wave-uniform base + lane*16
typedef __attribute__((address_space(1))) const unsigned int as1_uint;
typedef __attribute__((address_space(3))) unsigned int as3_uint;
__device__ __forceinline__ void gl_lds16(const ushort_t* g, ushort_t* l) {
  __builtin_amdgcn_global_load_lds((as1_uint*)g, (as3_uint*)l, 16, 0, 0);
}

// ---------------------------------------------------------------------------
// Fused prep: converts (img, topic) + 7 weight transposes (validated R18/R19).
// ---------------------------------------------------------------------------
__device__ __forceinline__ void trans_tile(
    const float* __restrict__ in, ushort_t* __restrict__ out,
    int r0, int R, int C, int Rp, int Cp, int bx, int by)
{
  __shared__ float tile[64][65];
  const int t = threadIdx.x;
  const int lc = t & 63, g = t >> 6;
  const int rbase = by * 64, cbase = bx * 64;
#pragma unroll
  for (int i = 0; i < 16; ++i) {
    int lr = g + 4 * i;
    int rr = rbase + lr, cc = cbase + lc;
    tile[lr][lc] = (rr < R && cc < C) ? in[(size_t)(r0 + rr) * C + cc] : 0.f;
  }
  __syncthreads();
#pragma unroll
  for (int i = 0; i < 16; ++i) {
    int wr2 = g + 4 * i;
    int oc = cbase + wr2, orr = rbase + lc;
    if (oc < Cp && orr < Rp)
      out[(size_t)oc * Rp + orr] = f2bf(tile[lc][wr2]);
  }
}

#define CONV_NB_IMG  2304
#define CONV_NB_TOP  4000
#define CONV_TOTAL   6304
#define TJ1_OFF 0
#define TJ2_OFF 256
#define TJ3_OFF 512
#define TJ4_OFF 592
#define TJ5_OFF 672
#define TJ6_OFF 2016
#define TJ7_OFF 2456
#define TJ_TOTAL 3800
#define PREP_TOTAL (CONV_TOTAL + TJ_TOTAL)

__global__ __launch_bounds__(256) void prep_all_k(
    const float* __restrict__ img, ushort_t* __restrict__ img_bf,
    const float* __restrict__ topic, ushort_t* __restrict__ topic_bf,
    const float* __restrict__ Wy_img, ushort_t* __restrict__ WyT_img,
    const float* __restrict__ Wg_img, ushort_t* __restrict__ WgT_img,
    const float* __restrict__ Wy_t,  ushort_t* __restrict__ WyT_t,
    const float* __restrict__ Wg_t,  ushort_t* __restrict__ WgT_t,
    const float* __restrict__ W1,    ushort_t* __restrict__ W1T_top,
    ushort_t* __restrict__ W1T_bot,
    const float* __restrict__ W2,    ushort_t* __restrict__ W2T)
{
  const int bid0 = blockIdx.x;
  if (bid0 < CONV_NB_IMG) {
    int i = bid0 * 256 + threadIdx.x;
    float4 v = reinterpret_cast<const float4*>(img)[i];
    ushort4 o;
    o.x = f2bf(v.x); o.y = f2bf(v.y); o.z = f2bf(v.z); o.w = f2bf(v.w);
    reinterpret_cast<ushort4*>(img_bf)[i] = o;
    return;
  }
  if (bid0 < CONV_TOTAL) {
    const int npc = TDIMP_ >> 2;
    int i = (bid0 - CONV_NB_IMG) * 256 + threadIdx.x;
    int row = i / npc, c4 = (i - row * npc) << 2;
    ushort4 o = make_ushort4(0, 0, 0, 0);
    if (c4 < TDIM_) {
      float4 v = *reinterpret_cast<const float4*>(&topic[(size_t)row * TDIM_ + c4]);
      o.x = f2bf(v.x); o.y = f2bf(v.y); o.z = f2bf(v.z); o.w = f2bf(v.w);
    }
    *reinterpret_cast<ushort4*>(&topic_bf[(size_t)row * TDIMP_ + c4]) = o;
    return;
  }
  const int bid = bid0 - CONV_TOTAL;
  if (bid < TJ2_OFF) {
    int l = bid - TJ1_OFF;
    trans_tile(Wy_img, WyT_img, 0, 2048, 512, 2048, 512, l % 8, l / 8);
  } else if (bid < TJ3_OFF) {
    int l = bid - TJ2_OFF;
    trans_tile(Wg_img, WgT_img, 0, 2048, 512, 2048, 512, l % 8, l / 8);
  } else if (bid < TJ4_OFF) {
    int l = bid - TJ3_OFF;
    trans_tile(Wy_t, WyT_t, 0, 600, 512, TDIMP_, 512, l % 8, l / 8);
  } else if (bid < TJ5_OFF) {
    int l = bid - TJ4_OFF;
    trans_tile(Wg_t, WgT_t, 0, 600, 512, TDIMP_, 512, l % 8, l / 8);
  } else if (bid < TJ6_OFF) {
    int l = bid - TJ5_OFF;
    trans_tile(W1, W1T_top, 0, 2048, CAT_, 2048, CATP_R, l % 42, l / 42);
  } else if (bid < TJ7_OFF) {
    int l = bid - TJ6_OFF;
    trans_tile(W1, W1T_bot, 2048, 600, CAT_, TDIMP_, CATP_R8, l % 44, l / 44);
  } else {
    int l = bid - TJ7_OFF;
    trans_tile(W2, W2T, 0, CAT_, 2048, CATP_K, 2048, l % 32, l / 32);
  }
}

// ---------------------------------------------------------------------------
// mid_all_k: fused {gated img, gated topic, himg 128^2 GEMM} (validated R19).
// ---------------------------------------------------------------------------
__device__ __forceinline__ void gated_body(
    ushort_t* __restrict__ smem,
    const ushort_t* __restrict__ A,
    const ushort_t* __restrict__ ByT, const ushort_t* __restrict__ BgT,
    const float* __restrict__ by, const float* __restrict__ bg,
    ushort_t* __restrict__ out, int M, int Kp, int bx, int byi)
{
  ushort_t* Als = smem;
  ushort_t* Bls = smem + 8192;
  const int tid = threadIdx.x;
  const int lane = tid & 63, w = tid >> 6;
  const int wr = w >> 1, wc = w & 1;
  const int m0 = byi * 128, n0 = bx * 64;
  const int N = LSTM_;

  const int srow = lane >> 2;
  const int scol = (lane & 3) * 8;
  const ushort_t* gA0 = A + (size_t)(m0 + w * 32 + srow) * Kp + scol;
  const ushort_t* gA1 = gA0 + (size_t)16 * Kp;
  const ushort_t* gBm = (w >> 1) ? BgT : ByT;
  const ushort_t* gB0 = gBm + (size_t)(n0 + (w & 1) * 32 + srow) * Kp + scol;
  const ushort_t* gB1 = gB0 + (size_t)16 * Kp;
  const int dA0 = (w * 32) * 32, dA1 = (w * 32 + 16) * 32;
  const int dB0 = ((w & 1) * 32) * 32, dB1 = ((w & 1) * 32 + 16) * 32;
  const int bm = w >> 1;

#define STAGE_W(BUF, KOFF) do {                                   \
    gl_lds16(gA0 + (KOFF), Als + (BUF) * 4096 + dA0);             \
    gl_lds16(gA1 + (KOFF), Als + (BUF) * 4096 + dA1);             \
    gl_lds16(gB0 + (KOFF), Bls + (BUF) * 4096 + bm * 2048 + dB0); \
    gl_lds16(gB1 + (KOFF), Bls + (BUF) * 4096 + bm * 2048 + dB1); \
  } while (0)

  f32x4 accy[4][2] = {}, accg[4][2] = {};
  short8 af[4], byf[2], bgf[2];

#define GATED_COMP(BUF) do {                                                  \
    _Pragma("unroll")                                                         \
    for (int i = 0; i < 4; ++i)                                               \
      af[i] = *reinterpret_cast<const short8*>(                               \
          Als + (BUF) * 4096 +                                                \
          (wr * 64 + i * 16 + (lane & 15)) * 32 + (lane >> 4) * 8);           \
    _Pragma("unroll")                                                         \
    for (int j = 0; j < 2; ++j) {                                             \
      int boff = (wc * 32 + j * 16 + (lane & 15)) * 32 + (lane >> 4) * 8;     \
      byf[j] = *reinterpret_cast<const short8*>(Bls + (BUF) * 4096 + boff);   \
      bgf[j] = *reinterpret_cast<const short8*>(Bls + (BUF) * 4096 + 2048 + boff); \
    }                                                                         \
    _Pragma("unroll")                                                         \
    for (int i = 0; i < 4; ++i)                                               \
      _Pragma("unroll")                                                       \
      for (int j = 0; j < 2; ++j) {                                           \
        accy[i][j] = __builtin_amdgcn_mfma_f32_16x16x32_bf16(af[i], byf[j], accy[i][j], 0, 0, 0); \
        accg[i][j] = __builtin_amdgcn_mfma_f32_16x16x32_bf16(af[i], bgf[j], accg[i][j], 0, 0, 0); \
      }                                                                       \
  } while (0)

  STAGE_W(0, 0);
  __syncthreads();
  int kb = 0;
  const int nt2 = Kp >> 6;
  for (int i = 0; i < nt2 - 1; ++i) {
    STAGE_W(1, kb + 32);
    GATED_COMP(0);
    __syncthreads();
    STAGE_W(0, kb + 64);
    GATED_COMP(1);
    __syncthreads();
    kb += 64;
  }
  STAGE_W(1, kb + 32);
  GATED_COMP(0);
  __syncthreads();
  GATED_COMP(1);
#undef STAGE_W
#undef GATED_COMP

  const int crow = (lane >> 4) * 4, ccol = lane & 15;
#pragma unroll
  for (int i = 0; i < 4; ++i)
#pragma unroll
    for (int j = 0; j < 2; ++j)
#pragma unroll
      for (int q = 0; q < 4; ++q) {
        int gm = m0 + wr * 64 + i * 16 + crow + q;
        int gn = n0 + wc * 32 + j * 16 + ccol;
        if (gm >= M || gn >= N) continue;
        float y = tanhf(accy[i][j][q] + by[gn]);
        float g = accg[i][j][q] + bg[gn];
        g = (g > 0.f) ? g : 0.01f * g;
        out[(size_t)gm * N + gn] = f2bf(y * g);
      }
}

__device__ __forceinline__ void gemm128_body(
    ushort_t* __restrict__ smem,
    const ushort_t* __restrict__ A, const ushort_t* __restrict__ BT,
    float* __restrict__ outf, int M, int Kp, int N, int bx, int by)
{
  ushort_t* Als = smem;
  ushort_t* Bls = smem + 8192;
  const int tid = threadIdx.x;
  const int lane = tid & 63, w = tid >> 6;
  const int wr = w >> 1, wc = w & 1;
  const int m0 = by * 128, n0 = bx * 128;

  const int srow = lane >> 2;
  const int scol = (lane & 3) * 8;
  const ushort_t* gA0 = A + (size_t)(m0 + w * 32 + srow) * Kp + scol;
  const ushort_t* gA1 = gA0 + (size_t)16 * Kp;
  const ushort_t* gB0 = BT + (size_t)(n0 + w * 32 + srow) * Kp + scol;
  const ushort_t* gB1 = gB0 + (size_t)16 * Kp;
  const int d0 = (w * 32) * 32, d1 = (w * 32 + 16) * 32;

#define STAGE_G(BUF, KOFF) do {                           \
    gl_lds16(gA0 + (KOFF), Als + (BUF) * 4096 + d0);      \
    gl_lds16(gA1 + (KOFF), Als + (BUF) * 4096 + d1);      \
    gl_lds16(gB0 + (KOFF), Bls + (BUF) * 4096 + d0);      \
    gl_lds16(gB1 + (KOFF), Bls + (BUF) * 4096 + d1);      \
  } while (0)

  f32x4 acc[4][4] = {};
  short8 af[4], bfv[4];

#define GEMM_COMP(BUF) do {                                                   \
    _Pragma("unroll")                                                         \
    for (int i = 0; i < 4; ++i)                                               \
      af[i] = *reinterpret_cast<const short8*>(                               \
          Als + (BUF) * 4096 +                                                \
          (wr * 64 + i * 16 + (lane & 15)) * 32 + (lane >> 4) * 8);           \
    _Pragma("unroll")                                                         \
    for (int j = 0; j < 4; ++j)                                               \
      bfv[j] = *reinterpret_cast<const short8*>(                              \
          Bls + (BUF) * 4096 +                                                \
          (wc * 64 + j * 16 + (lane & 15)) * 32 + (lane >> 4) * 8);           \
    _Pragma("unroll")                                                         \
    for (int i = 0; i < 4; ++i)                                               \
      _Pragma("unroll")                                                       \
      for (int j = 0; j < 4; ++j)                                             \
        acc[i][j] = __builtin_amdgcn_mfma_f32_16x16x32_bf16(af[i], bfv[j], acc[i][j], 0, 0, 0); \
  } while (0)

  STAGE_G(0, 0);
  __syncthreads();
  int kb = 0;
  const int nt2 = Kp >> 6;
  for (int i = 0; i < nt2 - 1; ++i) {
    STAGE_G(1, kb + 32);
    GEMM_COMP(0);
    __syncthreads();
    STAGE_G(0, kb + 64);
    GEMM_COMP(1);
    __syncthreads();
    kb += 64;
  }
  STAGE_G(1, kb + 32);
  GEMM_COMP(0);
  __syncthreads();
  GEMM_COMP(1);
#undef STAGE_G
#undef GEMM_COMP

  const int crow = (lane >> 4) * 4, ccol = lane & 15;
#pragma unroll
  for (int i = 0; i < 4; ++i)
#pragma unroll
    for (int j = 0; j < 4; ++j)
#pragma unroll
      for (int q = 0; q < 4; ++q) {
        int gm = m0 + wr * 64 + i * 16 + crow + q;
        int gn = n0 + wc * 64 + j * 16 + ccol;
        if (gm < M && gn < N) outf[(size_t)gm * N + gn] = acc[i][j][q];
      }
}

#define GB_IMG 72
#define GB_TOP 400
#define HB_NB  189
#define MID_TOTAL (GB_IMG + GB_TOP + HB_NB)

__global__ __launch_bounds__(256) void mid_all_k(
    const ushort_t* __restrict__ img_bf,
    const ushort_t* __restrict__ WyT_img, const ushort_t* __restrict__ WgT_img,
    const float* __restrict__ by_img, const float* __restrict__ bg_img,
    ushort_t* __restrict__ v_feat,
    const ushort_t* __restrict__ topic_bf,
    const ushort_t* __restrict__ WyT_t, const ushort_t* __restrict__ WgT_t,
    const float* __restrict__ by_t, const float* __restrict__ bg_t,
    ushort_t* __restrict__ topic_ft,
    const ushort_t* __restrict__ W1T_top, float* __restrict__ himg)
{
  __shared__ ushort_t smem[16384];
  const int bid = blockIdx.x;
  if (bid < GB_IMG) {
    gated_body(smem, img_bf, WyT_img, WgT_img, by_img, bg_img, v_feat,
               1152, 2048, bid & 7, bid >> 3);
  } else if (bid < GB_IMG + GB_TOP) {
    const int l = bid - GB_IMG;
    gated_body(smem, topic_bf, WyT_t, WgT_t, by_t, bg_t, topic_ft,
               6400, TDIMP_, l & 7, l >> 3);
  } else {
    const int l = bid - GB_IMG - GB_TOP;
    gemm128_body(smem, img_bf, W1T_top, himg, 1152, 2048, CAT_,
                 l % 21, l / 21);
  }
}

// ---------------------------------------------------------------------------
// 8-phase 256-wide GEMM body, v3 schedule (validated R12..R25), templated on
// MF = M-fragments per wave (BM = MF*32). MF=8: 256x256. MF=6: 192x256.
// ---------------------------------------------------------------------------
template<int MF>
__device__ __forceinline__ void gemm8_body(
    ushort_t* __restrict__ lds8, int bx, int by,
    const ushort_t* __restrict__ A, const ushort_t* __restrict__ BT,
    const float* __restrict__ bias, const float* __restrict__ D,
    float* __restrict__ outf, ushort_t* __restrict__ outb,
    int M, int Kp, int N, int ldOutb, int mode, int base)
{
  const int tid = threadIdx.x;
  const int lane = tid & 63, w = tid >> 6;
  const int wr = w >> 2, wc = w & 3;     // 2M x 4N waves
  const int m0 = by * (MF * 32), n0 = bx * 256;
  const int r15 = lane & 15, lg = lane >> 4;

  // staging source coords (inverse-swizzled)
  const int pr = lane >> 3, hh = lane & 7;
  const int cc = hh ^ pr;
  const int srow_l = (pr << 1) | (cc >> 2);
  const int scol_l = (cc & 3) << 3;

#define STAGE8(b_, s_, kt_) do {                                             \
    const ushort_t* src_ = ((s_) & 1) ? BT : A;                              \
    const int rowb_ = ((s_) & 1) ? n0 : m0;                                  \
    const int kcol_ = (kt_) * 64 + ((s_) >> 1) * 32 + scol_l;                \
    ushort_t* dst_ = &lds8[(b_) * 32768 + (s_) * 8192];                      \
    _Pragma("unroll")                                                        \
    for (int i_ = 0; i_ < 2; ++i_) {                                         \
      int grow_ = rowb_ + w * 32 + i_ * 16 + srow_l;                         \
      gl_lds16(src_ + (size_t)grow_ * Kp + kcol_,                            \
               &dst_[(w * 32 + i_ * 16) * 32]);                              \
    }                                                                        \
  } while (0)

#define LDS_RD(b_, s_, row_) (*reinterpret_cast<const short8*>(              \
    &lds8[(b_) * 32768 + (s_) * 8192 + ((row_) >> 1) * 64 +                  \
          (((((row_) & 1) << 2) | lg) ^ (((row_) >> 1) & 7)) * 8]))

  f32x4 acc[MF][4] = {};
  short8 aR0[MF], aR1[MF];
  short8 bR0[2], bR1[2];
  const int NT = Kp >> 6;

#define PHASE_WAIT() do {                                   \
    asm volatile("s_waitcnt vmcnt(4)" ::: "memory");        \
    __builtin_amdgcn_s_barrier();                           \
    __builtin_amdgcn_sched_barrier(0);                      \
  } while (0)

#define PRELOAD_A(ar_, b_, ks_) do {                                        \
    _Pragma("unroll")                                                       \
    for (int mf_ = 0; mf_ < MF; ++mf_)                                      \
      ar_[mf_] = LDS_RD(b_, (ks_) * 2, wr * (MF * 16) + mf_ * 16 + r15);    \
  } while (0)

#define PRELOAD_B(br_, b_, ks_, nfb_) do {                                  \
    br_[0] = LDS_RD(b_, (ks_) * 2 + 1, wc * 64 + (nfb_) * 16 + r15);        \
    br_[1] = LDS_RD(b_, (ks_) * 2 + 1, wc * 64 + ((nfb_) + 1) * 16 + r15);  \
  } while (0)

#define MFMA_G(ar_, br_, nfb_) do {                                         \
    __builtin_amdgcn_sched_barrier(0);                                      \
    __builtin_amdgcn_s_setprio(1);                                          \
    _Pragma("unroll")                                                       \
    for (int mf_ = 0; mf_ < MF; ++mf_) {                                    \
      acc[mf_][(nfb_)] = __builtin_amdgcn_mfma_f32_16x16x32_bf16(           \
          ar_[mf_], br_[0], acc[mf_][(nfb_)], 0, 0, 0);                     \
      acc[mf_][(nfb_) + 1] = __builtin_amdgcn_mfma_f32_16x16x32_bf16(       \
          ar_[mf_], br_[1], acc[mf_][(nfb_) + 1], 0, 0, 0);                 \
    }                                                                       \
    __builtin_amdgcn_s_setprio(0);                                          \
    __builtin_amdgcn_sched_barrier(0);                                      \
  } while (0)

  // prologue: stage tile 0 into buf 0; drain; preload phase-0 regs
  STAGE8(0, 0, 0); STAGE8(0, 1, 0); STAGE8(0, 2, 0); STAGE8(0, 3, 0);
  asm volatile("s_waitcnt vmcnt(0)" ::: "memory");
  __builtin_amdgcn_s_barrier();
  __builtin_amdgcn_sched_barrier(0);
  PRELOAD_A(aR0, 0, 0);
  PRELOAD_B(bR0, 0, 0, 0);

  for (int T = 0; T < NT - 1; ++T) {
    const int b = T & 1, nb = b ^ 1;
    STAGE8(nb, 0, T + 1);
    PHASE_WAIT();
    PRELOAD_B(bR1, b, 0, 2);
    MFMA_G(aR0, bR0, 0);
    STAGE8(nb, 1, T + 1);
    PHASE_WAIT();
    PRELOAD_A(aR1, b, 1);
    PRELOAD_B(bR0, b, 1, 0);
    MFMA_G(aR0, bR1, 2);
    STAGE8(nb, 2, T + 1);
    PHASE_WAIT();
    PRELOAD_B(bR1, b, 1, 2);
    MFMA_G(aR1, bR0, 0);
    STAGE8(nb, 3, T + 1);
    PHASE_WAIT();
    PRELOAD_A(aR0, nb, 0);
    PRELOAD_B(bR0, nb, 0, 0);
    MFMA_G(aR1, bR1, 2);
  }
  {
    asm volatile("s_waitcnt vmcnt(0)" ::: "memory");
    __builtin_amdgcn_s_barrier();
    __builtin_amdgcn_sched_barrier(0);
    const int b = (NT - 1) & 1;
    PRELOAD_B(bR1, b, 0, 2);
    MFMA_G(aR0, bR0, 0);
    PRELOAD_A(aR1, b, 1);
    PRELOAD_B(bR0, b, 1, 0);
    MFMA_G(aR0, bR1, 2);
    PRELOAD_B(bR1, b, 1, 2);
    MFMA_G(aR1, bR0, 0);
    MFMA_G(aR1, bR1, 2);
  }
#undef STAGE8
#undef PHASE_WAIT
#undef PRELOAD_A
#undef PRELOAD_B
#undef MFMA_G
#undef LDS_RD

  // epilogue write: C/D frag layout col=lane&15, row=(lane>>4)*4+q
  const int crow = lg * 4;
#pragma unroll
  for (int mf = 0; mf < MF; ++mf) {
#pragma unroll
    for (int nf = 0; nf < 4; ++nf) {
#pragma unroll
      for (int q = 0; q < 4; ++q) {
        int gm = m0 + wr * (MF * 16) + mf * 16 + crow + q;
        int gn = n0 + wc * 64 + nf * 16 + r15;
        if (gm >= M) continue;
        float v = acc[mf][nf][q];
        if (mode == 1) {
          if (gn < ldOutb) {
            float vv = 0.f;
            if (gn < N) {
              int g = base + gm;
              int drow = (g / 360) * 36 + (g % 36);
              vv = v + D[(size_t)drow * CAT_ + gn] + bias[gn];
              vv = vv > 0.f ? vv : 0.f;
            }
            outb[(size_t)gm * ldOutb + gn] = f2bf(vv);
          }
        } else {
          if (gn < N) {
            float vv = v + bias[gn];
            outf[(size_t)gm * N + gn] = vv > 0.f ? vv : 0.f;
          }
        }
      }
    }
  }
}

// E launch, single chunk 8-phase (R23-validated fallback path).
#define E_NB 253   // 11 bx x 23 by
__global__ __launch_bounds__(512, 2) void mfma_gemm8_eswz_k(
    const ushort_t* __restrict__ A, const ushort_t* __restrict__ BT,
    const float* __restrict__ bias, const float* __restrict__ D,
    ushort_t* __restrict__ outb, int base)
{
  extern __shared__ ushort_t lds8[];
  const int bid = blockIdx.x;
  const int xcd = bid & 7, j = bid >> 3;
  const int wgid = (xcd < 5 ? xcd * 32 : 160 + (xcd - 5) * 31) + j;
  const int bx = wgid % 11, by = wgid / 11;
  gemm8_body<8>(lds8, bx, by, A, BT, bias, D, nullptr, outb,
                5760, TDIMP_, CAT_, CATP_K, 1, base);
}

// Merged E (both chunks, 506 blocks): chunk c = bid/253 (validated R24/R25).
__global__ __launch_bounds__(512, 2) void mfma_gemm8_e2_k(
    const ushort_t* __restrict__ vt_att, const ushort_t* __restrict__ BT,
    const float* __restrict__ bias, const float* __restrict__ D,
    ushort_t* __restrict__ h1c0, ushort_t* __restrict__ h1c1)
{
  extern __shared__ ushort_t lds8[];
  const int c = blockIdx.x < E_NB ? 0 : 1;
  const int bid = blockIdx.x - c * E_NB;
  const int xcd = bid & 7, j = bid >> 3;
  const int wgid = (xcd < 5 ? xcd * 32 : 160 + (xcd - 5) * 31) + j;
  const int bx = wgid % 11, by = wgid / 11;
  gemm8_body<8>(lds8, bx, by,
                vt_att + (size_t)c * 5760 * TDIMP_, BT, bias, D,
                nullptr, c ? h1c1 : h1c0,
                5760, TDIMP_, CAT_, CATP_K, 1, c * 5760);
}

// F launch at BM=192 (MF=6), validated R25: 240 blocks, T1 swizzle.
#define F192_NB 240
__global__ __launch_bounds__(512, 2) void mfma_gemm8_f192_k(
    const ushort_t* __restrict__ h1, const ushort_t* __restrict__ W2T,
    const float* __restrict__ b2, float* __restrict__ outf)
{
  extern __shared__ ushort_t lds8[];
  const int bid = blockIdx.x;
  const int swz = (bid & 7) * 30 + (bid >> 3);   // bijective on [0,240)
  const int bx = swz & 7, by = swz >> 3;
  gemm8_body<6>(lds8, bx, by, h1, W2T, b2, nullptr, outf, nullptr,
                5760, CATP_K, 2048, 0, 2, 0);
}

// ---------------------------------------------------------------------------
// Fused attention v2 (validated R20): short8 score loads.
// ---------------------------------------------------------------------------
__global__ __launch_bounds__(256) void attn_fuse_k(
    const ushort_t* __restrict__ v_feat,
    const ushort_t* __restrict__ topic_feat,
    const float* __restrict__ topic_raw,
    const int*   __restrict__ qnp,
    ushort_t* __restrict__ vt_att)
{
  const int b  = blockIdx.x;
  const int ib = b / NUM_R_;
  __shared__ float tr[SL_Q_][TDIM_];
  __shared__ float msk[SL_Q_];

  const int tid = threadIdx.x;
  {
    const float4* g = reinterpret_cast<const float4*>(topic_raw + (size_t)b * SL_Q_ * TDIM_);
    float4* s = reinterpret_cast<float4*>(&tr[0][0]);
    for (int i = tid; i < SL_Q_ * TDIM_ / 4; i += 256) s[i] = g[i];
  }
  if (tid < SL_Q_) msk[tid] = (float)qnp[b * SL_Q_ + tid];
  __syncthreads();

  const int wave = tid >> 6, lane = tid & 63;
  const ushort_t* tf_b = topic_feat + (size_t)b * SL_Q_ * LSTM_;

  for (int p = wave; p < NUM_P_; p += 4) {
    const ushort_t* v = v_feat + ((size_t)ib * NUM_P_ + p) * LSTM_;
    float vr[8];
    {
      short8 vv = *reinterpret_cast<const short8*>(&v[lane * 8]);
#pragma unroll
      for (int k = 0; k < 8; ++k) vr[k] = bf2f((ushort_t)vv[k]);
    }

    float sc[SL_Q_];
#pragma unroll
    for (int s = 0; s < SL_Q_; ++s) {
      short8 tv = *reinterpret_cast<const short8*>(&tf_b[(size_t)s * LSTM_ + lane * 8]);
      float acc = 0.f;
#pragma unroll
      for (int k = 0; k < 8; ++k) acc += vr[k] * bf2f((ushort_t)tv[k]);
#pragma unroll
      for (int off = 32; off > 0; off >>= 1) acc += __shfl_xor(acc, off, 64);
      sc[s] = acc;
    }
    float mx = -1e30f;
#pragma unroll
    for (int s = 0; s < SL_Q_; ++s) {
      float m = msk[s];
      sc[s] = sc[s] * m + (m - 1.f) * 10000.f;
      mx = fmaxf(mx, sc[s]);
    }
    float sum = 0.f;
#pragma unroll
    for (int s = 0; s < SL_Q_; ++s) { sc[s] = expf(sc[s] - mx); sum += sc[s]; }
    const float inv = 1.f / sum;

    ushort_t* outp = vt_att + ((size_t)b * NUM_P_ + p) * TDIMP_;
    for (int t = lane; t < TDIMP_; t += 64) {
      float acc = 0.f;
      if (t < TDIM_) {
#pragma unroll
        for (int s = 0; s < SL_Q_; ++s) acc += sc[s] * tr[s][t];
        acc *= inv;
      }
      outp[t] = f2bf(t < TDIM_ ? acc : 0.f);
    }
  }
}

// ---------------------------------------------------------------------------
extern "C" void kernel_launch(void* const* d_in, const int* in_sizes, int n_in,
                              void* d_out, int out_size, void* d_ws, size_t ws_size,
                              hipStream_t stream) {
  const float* img    = (const float*)d_in[0];
  const float* topic  = (const float*)d_in[1];
  const int*   qnp    = (const int*)d_in[2];
  const float* Wy_img = (const float*)d_in[3];
  const float* by_img = (const float*)d_in[4];
  const float* Wg_img = (const float*)d_in[5];
  const float* bg_img = (const float*)d_in[6];
  const float* Wy_t   = (const float*)d_in[7];
  const float* by_t   = (const float*)d_in[8];
  const float* Wg_t   = (const float*)d_in[9];
  const float* bg_t   = (const float*)d_in[10];
  const float* W1     = (const float*)d_in[11];
  const float* b1     = (const float*)d_in[12];
  const float* W2     = (const float*)d_in[13];
  const float* b2     = (const float*)d_in[14];
  float* out = (float*)d_out;

  // --- workspace ---
  char* base = (char*)d_ws;
  size_t off = 0;
  auto alloc = [&](size_t bytes) {
    void* p = base + off;
    off += (bytes + 255) & ~(size_t)255;
    return p;
  };
  // region X (~37.2 MB): dead after mid phase; h1c0 (31.7 MB) aliases it
  ushort_t* img_bf    = (ushort_t*)alloc((size_t)1152 * 2048 * 2);
  ushort_t* topic_bf  = (ushort_t*)alloc((size_t)6400 * TDIMP_ * 2);
  ushort_t* WyT_img   = (ushort_t*)alloc((size_t)512 * 2048 * 2);
  ushort_t* WgT_img   = (ushort_t*)alloc((size_t)512 * 2048 * 2);
  ushort_t* WyT_t     = (ushort_t*)alloc((size_t)512 * TDIMP_ * 2);
  ushort_t* WgT_t     = (ushort_t*)alloc((size_t)512 * TDIMP_ * 2);
  ushort_t* W1T_top   = (ushort_t*)alloc((size_t)CATP_R * 2048 * 2);
  ushort_t* v_feat    = (ushort_t*)alloc((size_t)1152 * 512 * 2);
  ushort_t* topic_ft  = (ushort_t*)alloc((size_t)6400 * 512 * 2);
  // persistent
  ushort_t* W1T_bot   = (ushort_t*)alloc((size_t)CATP_R8 * TDIMP_ * 2);
  ushort_t* W2T       = (ushort_t*)alloc((size_t)2048 * CATP_K * 2);
  ushort_t* vt_att    = (ushort_t*)alloc((size_t)(11520 + 128) * TDIMP_ * 2);
  float*    himg      = (float*)alloc((size_t)1152 * CAT_ * 4);
  // second h1 chunk (31.7 MB) for the merged-E path (ws >= 110.6MB proven R21)
  ushort_t* h1c1      = (ushort_t*)alloc((size_t)5888 * CATP_K * 2);
  const bool merged   = (ws_size >= off);
  ushort_t* h1c0      = (ushort_t*)base;   // aliases region X (5888 x 2688)

  const dim3 blk(256);

  // --- phase A: fused prep ---
  prep_all_k<<<dim3(PREP_TOTAL), blk, 0, stream>>>(
      img, img_bf, topic, topic_bf,
      Wy_img, WyT_img, Wg_img, WgT_img, Wy_t, WyT_t, Wg_t, WgT_t,
      W1, W1T_top, W1T_bot, W2, W2T);

  // --- phase B: fused gated + himg ---
  mid_all_k<<<dim3(MID_TOTAL), blk, 0, stream>>>(
      img_bf, WyT_img, WgT_img, by_img, bg_img, v_feat,
      topic_bf, WyT_t, WgT_t, by_t, bg_t, topic_ft,
      W1T_top, himg);

  // --- phase C: attention ---
  attn_fuse_k<<<dim3(BS_ * NUM_R_), blk, 0, stream>>>(v_feat, topic_ft, topic, qnp, vt_att);

  if (merged) {
    // merged E (506 blocks), then two full-fill F-192 rounds (240 each)
    mfma_gemm8_e2_k<<<dim3(2 * E_NB), dim3(512), 131072, stream>>>(
        vt_att, W1T_bot, b1, himg, h1c0, h1c1);
    mfma_gemm8_f192_k<<<dim3(F192_NB), dim3(512), 131072, stream>>>(
        h1c0, W2T, b2, out);
    mfma_gemm8_f192_k<<<dim3(F192_NB), dim3(512), 131072, stream>>>(
        h1c1, W2T, b2, out + (size_t)5760 * IMG_F_);
  } else {
    // fallback: sequential chunks with single h1c0 (validated class)
    for (int c = 0; c < 2; ++c) {
      const int mbase = c * 5760;
      mfma_gemm8_eswz_k<<<dim3(E_NB), dim3(512), 131072, stream>>>(
          vt_att + (size_t)mbase * TDIMP_, W1T_bot, b1, himg, h1c0, mbase);
      mfma_gemm8_f192_k<<<dim3(F192_NB), dim3(512), 131072, stream>>>(
          h1c0, W2T, b2, out + (size_t)mbase * IMG_F_);
    }
  }
}